// Round 16
// baseline (406.060 us; speedup 1.0000x reference)
//
#include <hip/hip_runtime.h>

// TransformerConv x2 on MI355X — fused-launch 32x32 MFMA GEMM + atomic-free
// interleaved CSR-scatter, single-block scan+sort, degree-sorted 16-lane
// gather attention, bf16 skip. N=50000, E=800000, H=4, C=32, D=128.

#define TPB 256
#define SCT 768

typedef __attribute__((ext_vector_type(8))) short short8v;
typedef __attribute__((ext_vector_type(8))) unsigned short ushort8v;
typedef __attribute__((ext_vector_type(16))) float f32x16;

__device__ __forceinline__ unsigned short f2bf(float f) {
    unsigned u = __float_as_uint(f);
    u = (u + 0x7FFFu + ((u >> 16) & 1u)) >> 16;
    return (unsigned short)u;
}
__device__ __forceinline__ float bf2f(unsigned short s) {
    return __uint_as_float((unsigned)s << 16);
}
__device__ __forceinline__ float exp2_hw(float x) {
    float r;
    asm("v_exp_f32 %0, %1" : "=v"(r) : "v"(x));
    return r;
}

// ---- GEMM body (32x32x16): g = idx&3, row_tile = idx>>2 ----
__device__ __forceinline__ void gemm_body(
    int idx, int nrt,
    const unsigned short* __restrict__ A, int M,
    const unsigned short* __restrict__ pack,
    const float* __restrict__ bq, const float* __restrict__ bk,
    const float* __restrict__ bv, const float* __restrict__ bs,
    unsigned short* __restrict__ oq, unsigned short* __restrict__ okv,
    unsigned short* __restrict__ os)
{
    if (idx >= nrt * 4) return;
    const int g = idx & 3;
    const int row0 = (idx >> 2) * 128;

    const int wv = threadIdx.x >> 6;
    const int lane = threadIdx.x & 63;
    const int rbase = row0 + wv * 32;
    const int arow = rbase + (lane & 31);
    const int kh = (lane >> 5) * 8;

    const short8v z8 = {0, 0, 0, 0, 0, 0, 0, 0};
    short8v a[8];
    if (arow < M) {
        const unsigned short* Ap = A + (size_t)arow * 128 + kh;
#pragma unroll
        for (int t = 0; t < 8; ++t) a[t] = *(const short8v*)(Ap + t * 16);
    } else {
#pragma unroll
        for (int t = 0; t < 8; ++t) a[t] = z8;
    }

    f32x16 acc[4];
#pragma unroll
    for (int nc = 0; nc < 4; ++nc)
#pragma unroll
        for (int r = 0; r < 16; ++r) acc[nc][r] = 0.f;

    const unsigned short* bp = pack + (size_t)g * 16384;
#pragma unroll
    for (int nc = 0; nc < 4; ++nc) {
#pragma unroll
        for (int t = 0; t < 8; ++t) {
            short8v b = *(const short8v*)(bp + (nc * 8 + t) * 512 + lane * 8);
            acc[nc] = __builtin_amdgcn_mfma_f32_32x32x16_bf16(a[t], b, acc[nc], 0, 0, 0);
        }
    }

    const float* bias = g == 0 ? bq : (g == 1 ? bk : (g == 2 ? bv : bs));
    const int col = lane & 31;
    const int rb2 = rbase + 4 * (lane >> 5);
    unsigned short* out = g == 0 ? oq : (g == 3 ? os : okv);
    const int stride = (g == 1 || g == 2) ? 256 : 128;
    const int goff = g == 2 ? 128 : 0;
#pragma unroll
    for (int nc = 0; nc < 4; ++nc) {
        float bb = bias[nc * 32 + col];
#pragma unroll
        for (int r = 0; r < 16; ++r) {
            int row = rb2 + (r & 3) + 8 * (r >> 2);
            if (row < M)
                out[(size_t)row * stride + goff + nc * 32 + col] = f2bf(acc[nc][r] + bb);
        }
    }
}

// ---- scatter body: atomic-free. pos = row_ptr[dst] + edge_rank ----
__device__ __forceinline__ void scatter_body(
    int sb, const int* __restrict__ src, const int* __restrict__ dst,
    const float* __restrict__ ea, const int* __restrict__ row_ptr,
    const int* __restrict__ edge_rank,
    unsigned* __restrict__ csr_pack, int E)
{
    const int base = (sb * TPB + threadIdx.x) * 4;
    if (base + 3 < E) {
        int4 d4 = *(const int4*)(dst + base);
        int4 s4 = *(const int4*)(src + base);
        float4 a4 = *(const float4*)(ea + base);
        int4 r4 = *(const int4*)(edge_rank + base);
        csr_pack[row_ptr[d4.x] + r4.x] = ((unsigned)f2bf(a4.x) << 16) | (unsigned)s4.x;
        csr_pack[row_ptr[d4.y] + r4.y] = ((unsigned)f2bf(a4.y) << 16) | (unsigned)s4.y;
        csr_pack[row_ptr[d4.z] + r4.z] = ((unsigned)f2bf(a4.z) << 16) | (unsigned)s4.z;
        csr_pack[row_ptr[d4.w] + r4.w] = ((unsigned)f2bf(a4.w) << 16) | (unsigned)s4.w;
    } else {
        for (int e = base; e < E; ++e) {
            csr_pack[row_ptr[dst[e]] + edge_rank[e]] =
                ((unsigned)f2bf(ea[e]) << 16) | (unsigned)src[e];
        }
    }
}

// ---- fused: edge histogram w/ rank capture + weight prepack + x convert ----
__global__ void __launch_bounds__(TPB) hist_prep_cvt_k(
    const int* __restrict__ dst, int* __restrict__ deg,
    int* __restrict__ edge_rank, int E, int gE4,
    const float* __restrict__ Wq1, const float* __restrict__ Wk1,
    const float* __restrict__ Wv1, const float* __restrict__ Ws1,
    const float* __restrict__ Wq2, const float* __restrict__ Wk2,
    const float* __restrict__ Wv2, const float* __restrict__ Ws2,
    unsigned short* __restrict__ pack,
    const float* __restrict__ x, unsigned short* __restrict__ xb, int n4)
{
    if (blockIdx.x < (unsigned)gE4) {
        const int base = (blockIdx.x * TPB + threadIdx.x) * 4;
        if (base + 3 < E) {
            int4 d4 = *(const int4*)(dst + base);
            int4 r4;
            r4.x = atomicAdd(&deg[d4.x], 1);
            r4.y = atomicAdd(&deg[d4.y], 1);
            r4.z = atomicAdd(&deg[d4.z], 1);
            r4.w = atomicAdd(&deg[d4.w], 1);
            *(int4*)(edge_rank + base) = r4;
        } else {
            for (int e = base; e < E; ++e)
                edge_rank[e] = atomicAdd(&deg[dst[e]], 1);
        }
    } else if (blockIdx.x < (unsigned)(gE4 + 512)) {
        int i = (blockIdx.x - gE4) * TPB + threadIdx.x;   // 131072 total
        int j = i & 7, lane = (i >> 3) & 63, t = (i >> 9) & 7, nc = (i >> 12) & 3, g = (i >> 14) & 7;
        const float* Wt[8] = {Wq1, Wk1, Wv1, Ws1, Wq2, Wk2, Wv2, Ws2};
        const float* W = Wt[g];
        int kk = t * 16 + (lane >> 5) * 8 + j;
        int nn = nc * 32 + (lane & 31);
        pack[i] = f2bf(W[kk * 128 + nn]);
    } else {
        int i = (blockIdx.x - gE4 - 512) * TPB + threadIdx.x;
        if (i >= n4) return;
        float4 v = *(const float4*)(x + (size_t)i * 4);
        ushort4 o;
        o.x = f2bf(v.x); o.y = f2bf(v.y); o.z = f2bf(v.z); o.w = f2bf(v.w);
        *(ushort4*)(xb + (size_t)i * 4) = o;
    }
}

// ---- single-block: exclusive scan (row_ptr) + degree counting-sort (perm) ----
// 768 threads; per-thread-private LDS histogram columns (32 bins, ushort) —
// zero atomics. Prefix values <= N = 50000 fit ushort.
__global__ void __launch_bounds__(SCT) csr_scan_k(
    const int* __restrict__ deg, int n,
    int* __restrict__ row_ptr, int* __restrict__ perm)
{
    __shared__ unsigned short cnt[32 * SCT];   // 48 KB
    __shared__ int ts[SCT];
    const int t = threadIdx.x;
    const int C = (n + SCT - 1) / SCT;

#pragma unroll
    for (int b = 0; b < 32; ++b) cnt[b * SCT + t] = 0;

    // pass 1: local deg sums + private bin counts
    int s = 0;
    for (int j = 0; j < C; ++j) {
        int i = t * C + j;
        if (i < n) {
            int d = deg[i];
            s += d;
            cnt[(31 - min(d, 31)) * SCT + t]++;
        }
    }
    ts[t] = s;
    __syncthreads();
    for (int off = 1; off < SCT; off <<= 1) {
        int u = (t >= off) ? ts[t - off] : 0;
        __syncthreads();
        ts[t] += u;
        __syncthreads();
    }
    int run = ts[t] - s;
    for (int j = 0; j < C; ++j) {
        int i = t * C + j;
        if (i < n) {
            row_ptr[i] = run;
            run += deg[i];
            if (i == n - 1) row_ptr[n] = run;
        }
    }
    __syncthreads();

    // pass 2: exclusive scan of flattened cnt (32*SCT), 32-elem chunk/thread
    int s2 = 0;
    const int base2 = t * 32;
#pragma unroll
    for (int j = 0; j < 32; ++j) {
        int v = cnt[base2 + j];
        cnt[base2 + j] = (unsigned short)s2;
        s2 += v;
    }
    ts[t] = s2;
    __syncthreads();
    for (int off = 1; off < SCT; off <<= 1) {
        int u = (t >= off) ? ts[t - off] : 0;
        __syncthreads();
        ts[t] += u;
        __syncthreads();
    }
    int cb = ts[t] - s2;
#pragma unroll
    for (int j = 0; j < 32; ++j)
        cnt[base2 + j] = (unsigned short)(cnt[base2 + j] + cb);
    __syncthreads();

    // pass 3: emit perm (each thread owns its private cursor column)
    for (int j = 0; j < C; ++j) {
        int i = t * C + j;
        if (i < n) {
            int b = 31 - min(deg[i], 31);
            int p = cnt[b * SCT + t];
            cnt[b * SCT + t] = (unsigned short)(p + 1);
            perm[p] = i;
        }
    }
}

// ---- fused: interleaved atomic-free scatter + layer-1 GEMM (2:1 mix) ----
__global__ void __launch_bounds__(TPB) scatter_gemm_k(
    const int* __restrict__ src, const int* __restrict__ dst,
    const float* __restrict__ ea, const int* __restrict__ row_ptr,
    const int* __restrict__ edge_rank,
    unsigned* __restrict__ csr_pack, int E, int nSc,
    int nrt,
    const unsigned short* __restrict__ A, int M,
    const unsigned short* __restrict__ pack,
    const float* __restrict__ bq, const float* __restrict__ bk,
    const float* __restrict__ bv, const float* __restrict__ bs,
    unsigned short* __restrict__ oq, unsigned short* __restrict__ okv,
    unsigned short* __restrict__ os)
{
    const int b = blockIdx.x;
    const int n3 = b / 3, r = b - n3 * 3;
    if (b < 3 * nSc) {
        if (r == 2) scatter_body(n3, src, dst, ea, row_ptr, edge_rank, csr_pack, E);
        else gemm_body(2 * n3 + r, nrt, A, M, pack, bq, bk, bv, bs, oq, okv, os);
    } else {
        gemm_body(2 * nSc + (b - 3 * nSc), nrt, A, M, pack, bq, bk, bv, bs,
                  oq, okv, os);
    }
}

__global__ void __launch_bounds__(TPB) gemm_k(
    int nrt,
    const unsigned short* __restrict__ A, int M,
    const unsigned short* __restrict__ pack,
    const float* __restrict__ bq, const float* __restrict__ bk,
    const float* __restrict__ bv, const float* __restrict__ bs,
    unsigned short* __restrict__ oq, unsigned short* __restrict__ okv,
    unsigned short* __restrict__ os)
{
    gemm_body(blockIdx.x, nrt, A, M, pack, bq, bk, bv, bs, oq, okv, os);
}

// ---- gather attention: 16 lanes/node, 8-edge unroll, degree-sorted perm ----
template <bool BF16OUT>
__global__ void __launch_bounds__(TPB) node_attn_k(
    const unsigned short* __restrict__ q, const unsigned short* __restrict__ kv,
    const unsigned short* __restrict__ skip, const float* __restrict__ We,
    const int* __restrict__ row_ptr, const unsigned* __restrict__ csr_pack,
    const int* __restrict__ perm,
    void* __restrict__ outp, int n)
{
    const int slot = blockIdx.x * 16 + (threadIdx.x >> 4);
    if (slot >= n) return;
    const int node = perm[slot];
    const int l16 = threadIdx.x & 15;
    const int c8 = l16 * 8;

    const float C2 = 0.17677669529663687f * 1.44269504088896f; // 1/sqrt(32)*log2e

    float we8[8], qv[8];
    {
        float4 wlo = *(const float4*)(We + c8);
        float4 whi = *(const float4*)(We + c8 + 4);
        we8[0] = wlo.x; we8[1] = wlo.y; we8[2] = wlo.z; we8[3] = wlo.w;
        we8[4] = whi.x; we8[5] = whi.y; we8[6] = whi.z; we8[7] = whi.w;
        ushort8v qu = *(const ushort8v*)(q + (size_t)node * 128 + c8);
#pragma unroll
        for (int i = 0; i < 8; ++i) qv[i] = bf2f((unsigned short)qu[i]) * C2;
    }

    float qwe = 0.f;
#pragma unroll
    for (int i = 0; i < 8; ++i) qwe = fmaf(qv[i], we8[i], qwe);
    qwe += __shfl_xor(qwe, 1);
    qwe += __shfl_xor(qwe, 2);

    const int p0 = row_ptr[node], p1 = row_ptr[node + 1];

    float m = -3.4e38f, l = 0.f, sae = 0.f;
    float acc[8];
#pragma unroll
    for (int i = 0; i < 8; ++i) acc[i] = 0.f;

    for (int j = p0; j < p1; j += 8) {
        const int last = p1 - 1;
        unsigned pr[8];
#pragma unroll
        for (int t = 0; t < 8; ++t) pr[t] = csr_pack[min(j + t, last)];

        ushort8v ku[8], vu[8];
#pragma unroll
        for (int t = 0; t < 8; ++t) {
            const unsigned short* b = kv + (pr[t] & 0xFFFFu) * 256u + c8;
            ku[t] = *(const ushort8v*)b;
            vu[t] = *(const ushort8v*)(b + 128);
        }

        float d[8];
#pragma unroll
        for (int t = 0; t < 8; ++t) {
            float dd = 0.f;
#pragma unroll
            for (int i = 0; i < 8; ++i)
                dd = fmaf(bf2f((unsigned short)ku[t][i]), qv[i], dd);
            dd += __shfl_xor(dd, 1);
            dd += __shfl_xor(dd, 2);
            d[t] = dd;
        }

        float eav[8], al[8];
#pragma unroll
        for (int t = 0; t < 8; ++t) {
            eav[t] = bf2f((unsigned short)(pr[t] >> 16));
            al[t] = (t == 0 || j + t < p1) ? fmaf(eav[t], qwe, d[t]) : -3.4e38f;
        }

        float mn = m;
#pragma unroll
        for (int t = 0; t < 8; ++t) mn = fmaxf(mn, al[t]);
        float sc = exp2_hw(m - mn);
        float pe[8];
#pragma unroll
        for (int t = 0; t < 8; ++t) pe[t] = exp2_hw(al[t] - mn);

        float ls = 0.f, ss = 0.f;
#pragma unroll
        for (int t = 0; t < 8; ++t) { ls += pe[t]; ss = fmaf(pe[t], eav[t], ss); }
        l = fmaf(l, sc, ls);
        sae = fmaf(sae, sc, ss);
#pragma unroll
        for (int i = 0; i < 8; ++i) {
            float mv = 0.f;
#pragma unroll
            for (int t = 0; t < 8; ++t)
                mv = fmaf(pe[t], bf2f((unsigned short)vu[t][i]), mv);
            acc[i] = fmaf(acc[i], sc, mv);
        }
        m = mn;
    }

    float inv = 1.f / (l + 1e-16f);
    ushort8v sku = *(const ushort8v*)(skip + (size_t)node * 128 + c8);
    float o[8];
#pragma unroll
    for (int i = 0; i < 8; ++i)
        o[i] = fmaxf(fmaf(fmaf(sae, we8[i], acc[i]), inv,
                          bf2f((unsigned short)sku[i])), 0.f);

    if (BF16OUT) {
        ushort8v ov;
#pragma unroll
        for (int i = 0; i < 8; ++i) ov[i] = f2bf(o[i]);
        *(ushort8v*)((unsigned short*)outp + (size_t)node * 128 + c8) = ov;
    } else {
        float* op = (float*)outp + (size_t)node * 128 + c8;
        *(float4*)op = make_float4(o[0], o[1], o[2], o[3]);
        *(float4*)(op + 4) = make_float4(o[4], o[5], o[6], o[7]);
    }
}

extern "C" void kernel_launch(void* const* d_in, const int* in_sizes, int n_in,
                              void* d_out, int out_size, void* d_ws, size_t ws_size,
                              hipStream_t stream)
{
    const float* x   = (const float*)d_in[0];
    const int*   ei  = (const int*)d_in[1];
    const float* ea  = (const float*)d_in[2];
    const float* Wq1 = (const float*)d_in[3];  const float* bq1 = (const float*)d_in[4];
    const float* Wk1 = (const float*)d_in[5];  const float* bk1 = (const float*)d_in[6];
    const float* Wv1 = (const float*)d_in[7];  const float* bv1 = (const float*)d_in[8];
    const float* We1 = (const float*)d_in[9];
    const float* Ws1 = (const float*)d_in[10]; const float* bs1 = (const float*)d_in[11];
    const float* Wq2 = (const float*)d_in[12]; const float* bq2 = (const float*)d_in[13];
    const float* Wk2 = (const float*)d_in[14]; const float* bk2 = (const float*)d_in[15];
    const float* Wv2 = (const float*)d_in[16]; const float* bv2 = (const float*)d_in[17];
    const float* We2 = (const float*)d_in[18];
    const float* Ws2 = (const float*)d_in[19]; const float* bs2 = (const float*)d_in[20];

    const int N = in_sizes[0] / 128;
    const int E = in_sizes[1] / 2;
    const int* src = ei;
    const int* dst = ei + E;
    float* outf = (float*)d_out;

    // workspace layout
    unsigned short* q  = (unsigned short*)d_ws;          // N*128 bf16
    unsigned short* kv = q + (size_t)N * 128;            // N*256 bf16 (k|v)
    unsigned short* s  = kv + (size_t)N * 256;           // N*128 bf16 skip
    unsigned short* xb = s + (size_t)N * 128;            // bf16 x / h
    unsigned short* pk = xb + (size_t)N * 128;           // 131072 (both layers)
    int*   row_ptr = (int*)(pk + 131072);                // N+1
    int*   deg     = row_ptr + (N + 1);                  // N  (memset)
    int*   perm    = deg + N;                            // N
    int*   edge_rank = perm + N;                         // E
    unsigned* csr_pack = (unsigned*)(edge_rank + E);     // E

    const int gN16 = (N + 15) / 16;
    const int n4   = N * 128 / 4;
    const int gCv  = (n4 + TPB - 1) / TPB;
    const int gE4  = (E + 1023) / 1024;                  // 4 edges/thread blocks
    const int nrt  = (N + 127) / 128;                    // row tiles
    const int nGm  = nrt * 4;                            // gemm slots
    const int nSc  = gE4;                                // scatter blocks

    // 1) zero deg
    hipMemsetAsync(deg, 0, (size_t)N * sizeof(int), stream);
    // 2) fused hist(+rank) + prepack + cvt
    hist_prep_cvt_k<<<gE4 + 512 + gCv, TPB, 0, stream>>>(
        dst, deg, edge_rank, E, gE4,
        Wq1, Wk1, Wv1, Ws1, Wq2, Wk2, Wv2, Ws2, pk, x, xb, n4);
    // 3) single-block scan + sort
    csr_scan_k<<<1, SCT, 0, stream>>>(deg, N, row_ptr, perm);
    // 4) fused interleaved atomic-free scatter + layer-1 GEMM
    scatter_gemm_k<<<nSc + nGm, TPB, 0, stream>>>(
        src, dst, ea, row_ptr, edge_rank, csr_pack, E, nSc, nrt,
        xb, N, pk, bq1, bk1, bv1, bs1, q, kv, s);
    // 5) attn 1 (h -> bf16, reuse xb)
    node_attn_k<true><<<gN16, TPB, 0, stream>>>(q, kv, s, We1, row_ptr, csr_pack,
                                                perm, xb, N);
    // 6) layer-2 GEMM
    gemm_k<<<nGm, TPB, 0, stream>>>(nrt, xb, N, pk + 65536,
                                    bq2, bk2, bv2, bs2, q, kv, s);
    // 7) attn 2
    node_attn_k<false><<<gN16, TPB, 0, stream>>>(q, kv, s, We2, row_ptr, csr_pack,
                                                 perm, outf, N);
}

// Round 17
// 262.379 us; speedup vs baseline: 1.5476x; 1.5476x over previous
//
#include <hip/hip_runtime.h>

// TransformerConv x2 on MI355X — fused-launch 32x32 MFMA GEMM + atomic-free
// interleaved CSR-scatter, parallel scan chain, degree-sorted 16-lane
// gather attention, bf16 skip. N=50000, E=800000, H=4, C=32, D=128.
// (R15 configuration — R16's single-block scan regressed 161us, reverted.)

#define TPB 256

typedef __attribute__((ext_vector_type(8))) short short8v;
typedef __attribute__((ext_vector_type(8))) unsigned short ushort8v;
typedef __attribute__((ext_vector_type(16))) float f32x16;

__device__ __forceinline__ unsigned short f2bf(float f) {
    unsigned u = __float_as_uint(f);
    u = (u + 0x7FFFu + ((u >> 16) & 1u)) >> 16;
    return (unsigned short)u;
}
__device__ __forceinline__ float bf2f(unsigned short s) {
    return __uint_as_float((unsigned)s << 16);
}
__device__ __forceinline__ float exp2_hw(float x) {
    float r;
    asm("v_exp_f32 %0, %1" : "=v"(r) : "v"(x));
    return r;
}

// ---- GEMM body (32x32x16): g = idx&3, row_tile = idx>>2 ----
__device__ __forceinline__ void gemm_body(
    int idx, int nrt,
    const unsigned short* __restrict__ A, int M,
    const unsigned short* __restrict__ pack,
    const float* __restrict__ bq, const float* __restrict__ bk,
    const float* __restrict__ bv, const float* __restrict__ bs,
    unsigned short* __restrict__ oq, unsigned short* __restrict__ okv,
    unsigned short* __restrict__ os)
{
    if (idx >= nrt * 4) return;
    const int g = idx & 3;
    const int row0 = (idx >> 2) * 128;

    const int wv = threadIdx.x >> 6;
    const int lane = threadIdx.x & 63;
    const int rbase = row0 + wv * 32;
    const int arow = rbase + (lane & 31);
    const int kh = (lane >> 5) * 8;

    const short8v z8 = {0, 0, 0, 0, 0, 0, 0, 0};
    short8v a[8];
    if (arow < M) {
        const unsigned short* Ap = A + (size_t)arow * 128 + kh;
#pragma unroll
        for (int t = 0; t < 8; ++t) a[t] = *(const short8v*)(Ap + t * 16);
    } else {
#pragma unroll
        for (int t = 0; t < 8; ++t) a[t] = z8;
    }

    f32x16 acc[4];
#pragma unroll
    for (int nc = 0; nc < 4; ++nc)
#pragma unroll
        for (int r = 0; r < 16; ++r) acc[nc][r] = 0.f;

    const unsigned short* bp = pack + (size_t)g * 16384;
#pragma unroll
    for (int nc = 0; nc < 4; ++nc) {
#pragma unroll
        for (int t = 0; t < 8; ++t) {
            short8v b = *(const short8v*)(bp + (nc * 8 + t) * 512 + lane * 8);
            acc[nc] = __builtin_amdgcn_mfma_f32_32x32x16_bf16(a[t], b, acc[nc], 0, 0, 0);
        }
    }

    const float* bias = g == 0 ? bq : (g == 1 ? bk : (g == 2 ? bv : bs));
    const int col = lane & 31;
    const int rb2 = rbase + 4 * (lane >> 5);
    unsigned short* out = g == 0 ? oq : (g == 3 ? os : okv);
    const int stride = (g == 1 || g == 2) ? 256 : 128;
    const int goff = g == 2 ? 128 : 0;
#pragma unroll
    for (int nc = 0; nc < 4; ++nc) {
        float bb = bias[nc * 32 + col];
#pragma unroll
        for (int r = 0; r < 16; ++r) {
            int row = rb2 + (r & 3) + 8 * (r >> 2);
            if (row < M)
                out[(size_t)row * stride + goff + nc * 32 + col] = f2bf(acc[nc][r] + bb);
        }
    }
}

// ---- scatter body: atomic-free. pos = row_ptr[dst] + edge_rank ----
__device__ __forceinline__ void scatter_body(
    int sb, const int* __restrict__ src, const int* __restrict__ dst,
    const float* __restrict__ ea, const int* __restrict__ row_ptr,
    const int* __restrict__ edge_rank,
    unsigned* __restrict__ csr_pack, int E)
{
    const int base = (sb * TPB + threadIdx.x) * 4;
    if (base + 3 < E) {
        int4 d4 = *(const int4*)(dst + base);
        int4 s4 = *(const int4*)(src + base);
        float4 a4 = *(const float4*)(ea + base);
        int4 r4 = *(const int4*)(edge_rank + base);
        csr_pack[row_ptr[d4.x] + r4.x] = ((unsigned)f2bf(a4.x) << 16) | (unsigned)s4.x;
        csr_pack[row_ptr[d4.y] + r4.y] = ((unsigned)f2bf(a4.y) << 16) | (unsigned)s4.y;
        csr_pack[row_ptr[d4.z] + r4.z] = ((unsigned)f2bf(a4.z) << 16) | (unsigned)s4.z;
        csr_pack[row_ptr[d4.w] + r4.w] = ((unsigned)f2bf(a4.w) << 16) | (unsigned)s4.w;
    } else {
        for (int e = base; e < E; ++e) {
            csr_pack[row_ptr[dst[e]] + edge_rank[e]] =
                ((unsigned)f2bf(ea[e]) << 16) | (unsigned)src[e];
        }
    }
}

// ---- fused: edge histogram w/ rank capture + weight prepack + x convert ----
__global__ void __launch_bounds__(TPB) hist_prep_cvt_k(
    const int* __restrict__ dst, int* __restrict__ deg,
    int* __restrict__ edge_rank, int E, int gE4,
    const float* __restrict__ Wq1, const float* __restrict__ Wk1,
    const float* __restrict__ Wv1, const float* __restrict__ Ws1,
    const float* __restrict__ Wq2, const float* __restrict__ Wk2,
    const float* __restrict__ Wv2, const float* __restrict__ Ws2,
    unsigned short* __restrict__ pack,
    const float* __restrict__ x, unsigned short* __restrict__ xb, int n4)
{
    if (blockIdx.x < (unsigned)gE4) {
        const int base = (blockIdx.x * TPB + threadIdx.x) * 4;
        if (base + 3 < E) {
            int4 d4 = *(const int4*)(dst + base);
            int4 r4;
            r4.x = atomicAdd(&deg[d4.x], 1);
            r4.y = atomicAdd(&deg[d4.y], 1);
            r4.z = atomicAdd(&deg[d4.z], 1);
            r4.w = atomicAdd(&deg[d4.w], 1);
            *(int4*)(edge_rank + base) = r4;
        } else {
            for (int e = base; e < E; ++e)
                edge_rank[e] = atomicAdd(&deg[dst[e]], 1);
        }
    } else if (blockIdx.x < (unsigned)(gE4 + 512)) {
        int i = (blockIdx.x - gE4) * TPB + threadIdx.x;   // 131072 total
        int j = i & 7, lane = (i >> 3) & 63, t = (i >> 9) & 7, nc = (i >> 12) & 3, g = (i >> 14) & 7;
        const float* Wt[8] = {Wq1, Wk1, Wv1, Ws1, Wq2, Wk2, Wv2, Ws2};
        const float* W = Wt[g];
        int kk = t * 16 + (lane >> 5) * 8 + j;
        int nn = nc * 32 + (lane & 31);
        pack[i] = f2bf(W[kk * 128 + nn]);
    } else {
        int i = (blockIdx.x - gE4 - 512) * TPB + threadIdx.x;
        if (i >= n4) return;
        float4 v = *(const float4*)(x + (size_t)i * 4);
        ushort4 o;
        o.x = f2bf(v.x); o.y = f2bf(v.y); o.z = f2bf(v.z); o.w = f2bf(v.w);
        *(ushort4*)(xb + (size_t)i * 4) = o;
    }
}

// ---------------- CSR scan chain (parallel, R15 version) ----------------
__global__ void __launch_bounds__(TPB) scan_a_k(const int* __restrict__ deg, int n,
                                                int* __restrict__ incl,
                                                int* __restrict__ bsum,
                                                int* __restrict__ bcnt, int nb,
                                                int* __restrict__ rank)
{
    __shared__ int ts[TPB];
    __shared__ int lhist[64];
    if (threadIdx.x < 64) lhist[threadIdx.x] = 0;
    const int base = blockIdx.x * 1024;
    int vals[4], s = 0;
#pragma unroll
    for (int j = 0; j < 4; ++j) {
        int i = base + threadIdx.x * 4 + j;
        vals[j] = (i < n) ? deg[i] : 0;
        s += vals[j];
    }
    ts[threadIdx.x] = s;
    __syncthreads();
#pragma unroll
    for (int j = 0; j < 4; ++j) {
        int i = base + threadIdx.x * 4 + j;
        if (i < n) {
            int bin = 63 - min(vals[j], 63);   // descending degree order
            rank[i] = atomicAdd(&lhist[bin], 1);
        }
    }
    for (int off = 1; off < TPB; off <<= 1) {
        int u = (threadIdx.x >= off) ? ts[threadIdx.x - off] : 0;
        __syncthreads();
        ts[threadIdx.x] += u;
        __syncthreads();
    }
    int run = ts[threadIdx.x] - s;
#pragma unroll
    for (int j = 0; j < 4; ++j) {
        run += vals[j];
        int i = base + threadIdx.x * 4 + j;
        if (i < n) incl[i] = run;
    }
    if (threadIdx.x == TPB - 1) bsum[blockIdx.x] = ts[TPB - 1];
    __syncthreads();
    if (threadIdx.x < 64) bcnt[threadIdx.x * nb + blockIdx.x] = lhist[threadIdx.x];
}

__global__ void __launch_bounds__(TPB) scan_b_k(int* __restrict__ bsum, int nb,
                                                int* __restrict__ bcnt)
{
    __shared__ int ts[TPB];
    const int t = threadIdx.x;
    int v = (t < nb) ? bsum[t] : 0;
    ts[t] = v;
    __syncthreads();
    for (int off = 1; off < TPB; off <<= 1) {
        int u = (t >= off) ? ts[t - off] : 0;
        __syncthreads();
        ts[t] += u;
        __syncthreads();
    }
    if (t < nb) bsum[t] = ts[t] - v;
    __syncthreads();

    const int total = 64 * nb;
    const int C = (total + TPB - 1) / TPB;
    int loc[32];
    int s = 0;
    for (int j = 0; j < C; ++j) {
        int i = t * C + j;
        loc[j] = (i < total) ? bcnt[i] : 0;
        s += loc[j];
    }
    __syncthreads();
    ts[t] = s;
    __syncthreads();
    for (int off = 1; off < TPB; off <<= 1) {
        int u = (t >= off) ? ts[t - off] : 0;
        __syncthreads();
        ts[t] += u;
        __syncthreads();
    }
    int run = ts[t] - s;
    for (int j = 0; j < C; ++j) {
        int i = t * C + j;
        if (i < total) bcnt[i] = run;
        run += loc[j];
    }
}

__global__ void __launch_bounds__(TPB) finalize_k(const int* __restrict__ incl,
                                                  const int* __restrict__ deg,
                                                  const int* __restrict__ bsum, int n,
                                                  int* __restrict__ row_ptr,
                                                  const int* __restrict__ bcnt, int nb,
                                                  const int* __restrict__ rank,
                                                  int* __restrict__ perm)
{
    const int base = blockIdx.x * 1024;
    const int boff = bsum[blockIdx.x];
#pragma unroll
    for (int j = 0; j < 4; ++j) {
        int i = base + threadIdx.x * 4 + j;
        if (i < n) {
            int dg = deg[i];
            int iv = incl[i] + boff;
            row_ptr[i] = iv - dg;
            if (i == n - 1) row_ptr[n] = iv;
            int bin = 63 - min(dg, 63);
            perm[bcnt[bin * nb + blockIdx.x] + rank[i]] = i;
        }
    }
}

// ---- fused: interleaved atomic-free scatter + layer-1 GEMM (2:1 mix) ----
__global__ void __launch_bounds__(TPB) scatter_gemm_k(
    const int* __restrict__ src, const int* __restrict__ dst,
    const float* __restrict__ ea, const int* __restrict__ row_ptr,
    const int* __restrict__ edge_rank,
    unsigned* __restrict__ csr_pack, int E, int nSc,
    int nrt,
    const unsigned short* __restrict__ A, int M,
    const unsigned short* __restrict__ pack,
    const float* __restrict__ bq, const float* __restrict__ bk,
    const float* __restrict__ bv, const float* __restrict__ bs,
    unsigned short* __restrict__ oq, unsigned short* __restrict__ okv,
    unsigned short* __restrict__ os)
{
    const int b = blockIdx.x;
    const int n3 = b / 3, r = b - n3 * 3;
    if (b < 3 * nSc) {
        if (r == 2) scatter_body(n3, src, dst, ea, row_ptr, edge_rank, csr_pack, E);
        else gemm_body(2 * n3 + r, nrt, A, M, pack, bq, bk, bv, bs, oq, okv, os);
    } else {
        gemm_body(2 * nSc + (b - 3 * nSc), nrt, A, M, pack, bq, bk, bv, bs,
                  oq, okv, os);
    }
}

__global__ void __launch_bounds__(TPB) gemm_k(
    int nrt,
    const unsigned short* __restrict__ A, int M,
    const unsigned short* __restrict__ pack,
    const float* __restrict__ bq, const float* __restrict__ bk,
    const float* __restrict__ bv, const float* __restrict__ bs,
    unsigned short* __restrict__ oq, unsigned short* __restrict__ okv,
    unsigned short* __restrict__ os)
{
    gemm_body(blockIdx.x, nrt, A, M, pack, bq, bk, bv, bs, oq, okv, os);
}

// ---- gather attention: 16 lanes/node, 8-edge unroll, degree-sorted perm ----
template <bool BF16OUT>
__global__ void __launch_bounds__(TPB) node_attn_k(
    const unsigned short* __restrict__ q, const unsigned short* __restrict__ kv,
    const unsigned short* __restrict__ skip, const float* __restrict__ We,
    const int* __restrict__ row_ptr, const unsigned* __restrict__ csr_pack,
    const int* __restrict__ perm,
    void* __restrict__ outp, int n)
{
    const int slot = blockIdx.x * 16 + (threadIdx.x >> 4);
    if (slot >= n) return;
    const int node = perm[slot];
    const int l16 = threadIdx.x & 15;
    const int c8 = l16 * 8;

    const float C2 = 0.17677669529663687f * 1.44269504088896f; // 1/sqrt(32)*log2e

    float we8[8], qv[8];
    {
        float4 wlo = *(const float4*)(We + c8);
        float4 whi = *(const float4*)(We + c8 + 4);
        we8[0] = wlo.x; we8[1] = wlo.y; we8[2] = wlo.z; we8[3] = wlo.w;
        we8[4] = whi.x; we8[5] = whi.y; we8[6] = whi.z; we8[7] = whi.w;
        ushort8v qu = *(const ushort8v*)(q + (size_t)node * 128 + c8);
#pragma unroll
        for (int i = 0; i < 8; ++i) qv[i] = bf2f((unsigned short)qu[i]) * C2;
    }

    float qwe = 0.f;
#pragma unroll
    for (int i = 0; i < 8; ++i) qwe = fmaf(qv[i], we8[i], qwe);
    qwe += __shfl_xor(qwe, 1);
    qwe += __shfl_xor(qwe, 2);

    const int p0 = row_ptr[node], p1 = row_ptr[node + 1];

    float m = -3.4e38f, l = 0.f, sae = 0.f;
    float acc[8];
#pragma unroll
    for (int i = 0; i < 8; ++i) acc[i] = 0.f;

    for (int j = p0; j < p1; j += 8) {
        const int last = p1 - 1;
        unsigned pr[8];
#pragma unroll
        for (int t = 0; t < 8; ++t) pr[t] = csr_pack[min(j + t, last)];

        ushort8v ku[8], vu[8];
#pragma unroll
        for (int t = 0; t < 8; ++t) {
            const unsigned short* b = kv + (pr[t] & 0xFFFFu) * 256u + c8;
            ku[t] = *(const ushort8v*)b;
            vu[t] = *(const ushort8v*)(b + 128);
        }

        float d[8];
#pragma unroll
        for (int t = 0; t < 8; ++t) {
            float dd = 0.f;
#pragma unroll
            for (int i = 0; i < 8; ++i)
                dd = fmaf(bf2f((unsigned short)ku[t][i]), qv[i], dd);
            dd += __shfl_xor(dd, 1);
            dd += __shfl_xor(dd, 2);
            d[t] = dd;
        }

        float eav[8], al[8];
#pragma unroll
        for (int t = 0; t < 8; ++t) {
            eav[t] = bf2f((unsigned short)(pr[t] >> 16));
            al[t] = (t == 0 || j + t < p1) ? fmaf(eav[t], qwe, d[t]) : -3.4e38f;
        }

        float mn = m;
#pragma unroll
        for (int t = 0; t < 8; ++t) mn = fmaxf(mn, al[t]);
        float sc = exp2_hw(m - mn);
        float pe[8];
#pragma unroll
        for (int t = 0; t < 8; ++t) pe[t] = exp2_hw(al[t] - mn);

        float ls = 0.f, ss = 0.f;
#pragma unroll
        for (int t = 0; t < 8; ++t) { ls += pe[t]; ss = fmaf(pe[t], eav[t], ss); }
        l = fmaf(l, sc, ls);
        sae = fmaf(sae, sc, ss);
#pragma unroll
        for (int i = 0; i < 8; ++i) {
            float mv = 0.f;
#pragma unroll
            for (int t = 0; t < 8; ++t)
                mv = fmaf(pe[t], bf2f((unsigned short)vu[t][i]), mv);
            acc[i] = fmaf(acc[i], sc, mv);
        }
        m = mn;
    }

    float inv = 1.f / (l + 1e-16f);
    ushort8v sku = *(const ushort8v*)(skip + (size_t)node * 128 + c8);
    float o[8];
#pragma unroll
    for (int i = 0; i < 8; ++i)
        o[i] = fmaxf(fmaf(fmaf(sae, we8[i], acc[i]), inv,
                          bf2f((unsigned short)sku[i])), 0.f);

    if (BF16OUT) {
        ushort8v ov;
#pragma unroll
        for (int i = 0; i < 8; ++i) ov[i] = f2bf(o[i]);
        *(ushort8v*)((unsigned short*)outp + (size_t)node * 128 + c8) = ov;
    } else {
        float* op = (float*)outp + (size_t)node * 128 + c8;
        *(float4*)op = make_float4(o[0], o[1], o[2], o[3]);
        *(float4*)(op + 4) = make_float4(o[4], o[5], o[6], o[7]);
    }
}

extern "C" void kernel_launch(void* const* d_in, const int* in_sizes, int n_in,
                              void* d_out, int out_size, void* d_ws, size_t ws_size,
                              hipStream_t stream)
{
    const float* x   = (const float*)d_in[0];
    const int*   ei  = (const int*)d_in[1];
    const float* ea  = (const float*)d_in[2];
    const float* Wq1 = (const float*)d_in[3];  const float* bq1 = (const float*)d_in[4];
    const float* Wk1 = (const float*)d_in[5];  const float* bk1 = (const float*)d_in[6];
    const float* Wv1 = (const float*)d_in[7];  const float* bv1 = (const float*)d_in[8];
    const float* We1 = (const float*)d_in[9];
    const float* Ws1 = (const float*)d_in[10]; const float* bs1 = (const float*)d_in[11];
    const float* Wq2 = (const float*)d_in[12]; const float* bq2 = (const float*)d_in[13];
    const float* Wk2 = (const float*)d_in[14]; const float* bk2 = (const float*)d_in[15];
    const float* Wv2 = (const float*)d_in[16]; const float* bv2 = (const float*)d_in[17];
    const float* We2 = (const float*)d_in[18];
    const float* Ws2 = (const float*)d_in[19]; const float* bs2 = (const float*)d_in[20];

    const int N = in_sizes[0] / 128;
    const int E = in_sizes[1] / 2;
    const int* src = ei;
    const int* dst = ei + E;
    float* outf = (float*)d_out;

    const int nb = (N + 1023) / 1024;

    // workspace layout
    unsigned short* q  = (unsigned short*)d_ws;          // N*128 bf16
    unsigned short* kv = q + (size_t)N * 128;            // N*256 bf16 (k|v)
    unsigned short* s  = kv + (size_t)N * 256;           // N*128 bf16 skip
    unsigned short* xb = s + (size_t)N * 128;            // bf16 x / h
    unsigned short* pk = xb + (size_t)N * 128;           // 131072 (both layers)
    int*   row_ptr = (int*)(pk + 131072);                // N+1
    int*   deg     = row_ptr + (N + 1);                  // N  (memset)
    int*   incl    = deg + N;                            // N
    int*   rank    = incl + N;                           // N
    int*   bsum    = rank + N;                           // 256
    int*   bcnt    = bsum + 256;                         // 64*nb
    int*   perm    = bcnt + 64 * nb;                     // N
    int*   edge_rank = perm + N;                         // E
    unsigned* csr_pack = (unsigned*)(edge_rank + E);     // E

    const int gN16 = (N + 15) / 16;
    const int n4   = N * 128 / 4;
    const int gCv  = (n4 + TPB - 1) / TPB;
    const int gE4  = (E + 1023) / 1024;                  // 4 edges/thread blocks
    const int nrt  = (N + 127) / 128;                    // row tiles
    const int nGm  = nrt * 4;                            // gemm slots
    const int nSc  = gE4;                                // scatter blocks

    // 1) zero deg
    hipMemsetAsync(deg, 0, (size_t)N * sizeof(int), stream);
    // 2) fused hist(+rank) + prepack + cvt
    hist_prep_cvt_k<<<gE4 + 512 + gCv, TPB, 0, stream>>>(
        dst, deg, edge_rank, E, gE4,
        Wq1, Wk1, Wv1, Ws1, Wq2, Wk2, Wv2, Ws2, pk, x, xb, n4);
    // 3-5) parallel scan chain
    scan_a_k<<<nb, TPB, 0, stream>>>(deg, N, incl, bsum, bcnt, nb, rank);
    scan_b_k<<<1, TPB, 0, stream>>>(bsum, nb, bcnt);
    finalize_k<<<nb, TPB, 0, stream>>>(incl, deg, bsum, N, row_ptr,
                                       bcnt, nb, rank, perm);
    // 6) fused interleaved atomic-free scatter + layer-1 GEMM
    scatter_gemm_k<<<nSc + nGm, TPB, 0, stream>>>(
        src, dst, ea, row_ptr, edge_rank, csr_pack, E, nSc, nrt,
        xb, N, pk, bq1, bk1, bv1, bs1, q, kv, s);
    // 7) attn 1 (h -> bf16, reuse xb)
    node_attn_k<true><<<gN16, TPB, 0, stream>>>(q, kv, s, We1, row_ptr, csr_pack,
                                                perm, xb, N);
    // 8) layer-2 GEMM
    gemm_k<<<nGm, TPB, 0, stream>>>(nrt, xb, N, pk + 65536,
                                    bq2, bk2, bv2, bs2, q, kv, s);
    // 9) attn 2
    node_attn_k<false><<<gN16, TPB, 0, stream>>>(q, kv, s, We2, row_ptr, csr_pack,
                                                 perm, outf, N);
}